// Round 1
// 356.103 us; speedup vs baseline: 1.0241x; 1.0241x over previous
//
#include <hip/hip_runtime.h>
#include <hip/hip_bf16.h>

// GraphConvNorm: scatter-mean by (row*7+edge_type) -> [N,896]@[896,128] -> BatchNorm.
// N=100000, C=128, E=700000. x/w/gamma/beta f32, indices auto int32/int64, out f32.
// r6 profile: gather_k 120us top, latency-bound (VALU 24%, HBM 16%, dynamic edge loop
// => vmcnt(0) per edge). r7: unroll-4 edge loop, 8192 waves, standard-layout store.
// r8: gather_k was still latency-bound (99us, HBM 19%; Little's law: serial remainder
// loop => ~0.26 outstanding reqs/wave => 1.4 TB/s predicted ~= 1.55 measured).
// Fix: batch-8 predicated issue (nE is wave-uniform => scalar branches), per-node
// reciprocal (civ) instead of per-edge divide, and software-pipelined metadata
// prefetch (next node's fill/ebuf/cnt/self issued while edge loads are in flight).
// ws: y 179.2MB + wp 0.23 + cnt 2.8 + fill 0.4 + ebuf 12.8 + ovf 2.8 + stats ~1KB.

typedef float  f32x4  __attribute__((ext_vector_type(4)));
typedef short  short8 __attribute__((ext_vector_type(8)));
typedef __bf16 bf16x8 __attribute__((ext_vector_type(8)));

union BFrag { uint4 q; short8 s; bf16x8 b; unsigned int u[4]; };

__device__ inline unsigned short f2bfbits(float f) {
    union { float f; unsigned int u; } v; v.f = f;
    unsigned int u = v.u;
    u += 0x7fffu + ((u >> 16) & 1u);   // RNE
    return (unsigned short)(u >> 16);
}
__device__ inline unsigned int pk_bf16(float lo, float hi) {
    float2 f; f.x = lo; f.y = hi;
    union { __hip_bfloat162 h; unsigned int u; } v;
    v.h = __float22bfloat162_rn(f);
    return v.u;
}
__device__ inline float bflo(unsigned int p) {
    union { unsigned int u; float f; } v; v.u = p << 16; return v.f;
}
__device__ inline float bfhi(unsigned int p) {
    union { unsigned int u; float f; } v; v.u = p & 0xffff0000u; return v.f;
}

#define BUCKET_CAP 32

// ---- W [7*128,128] f32 -> bf16 in MFMA B-frag order: [t][nt][kc][lane][j] ----
__global__ void pack_w(const float* __restrict__ w, short8* __restrict__ wp)
{
    int u = blockIdx.x * 256 + threadIdx.x;
    if (u >= 7 * 8 * 4 * 64) return;
    int lane = u & 63, kc = (u >> 6) & 3, nt = (u >> 8) & 7, t = u >> 11;
    int quad = lane >> 4, lr = lane & 15;
    short8 s;
#pragma unroll
    for (int j = 0; j < 8; ++j)
        s[j] = (short)f2bfbits(w[(size_t)(t * 128 + kc * 32 + quad * 8 + j) * 128
                                 + nt * 16 + lr]);
    wp[u] = s;
}

// ---- GEMM: y[m][t] row = 64 u32, word p=lr*4+j holds channels (j*16+lr, +64) ----
__global__ __launch_bounds__(256) void gemm_xw(
    const float* __restrict__ x, const uint4* __restrict__ wpq,
    unsigned int* __restrict__ yu, int N)
{
    const int tid  = threadIdx.x;
    const int lane = tid & 63;
    const int wv   = tid >> 6;
    const int quad = lane >> 4;
    const int lr   = lane & 15;
    const int mbase = blockIdx.x * 128 + wv * 32;

    BFrag a[2][4];   // A[m=lr][k=quad*8+j], two 16-row groups
#pragma unroll
    for (int g = 0; g < 2; ++g)
#pragma unroll
        for (int kc = 0; kc < 4; ++kc) {
            const float* xr = x + (size_t)min(mbase + g * 16 + lr, N - 1) * 128
                              + kc * 32 + quad * 8;
            f32x4 v0 = *(const f32x4*)xr;
            f32x4 v1 = *(const f32x4*)(xr + 4);
            a[g][kc].u[0] = pk_bf16(v0[0], v0[1]);
            a[g][kc].u[1] = pk_bf16(v0[2], v0[3]);
            a[g][kc].u[2] = pk_bf16(v1[0], v1[1]);
            a[g][kc].u[3] = pk_bf16(v1[2], v1[3]);
        }

    for (int t = 0; t < 7; ++t) {
        f32x4 acc[2][8];
#pragma unroll
        for (int g = 0; g < 2; ++g)
#pragma unroll
            for (int nt = 0; nt < 8; ++nt) acc[g][nt] = (f32x4){0.f, 0.f, 0.f, 0.f};

#pragma unroll
        for (int nt = 0; nt < 8; ++nt)
#pragma unroll
            for (int kc = 0; kc < 4; ++kc) {
                BFrag b;
                b.q = wpq[(size_t)(((t * 8 + nt) * 4 + kc) * 64) + lane];
                acc[0][nt] = __builtin_amdgcn_mfma_f32_16x16x32_bf16(a[0][kc].b, b.b, acc[0][nt], 0, 0, 0);
                acc[1][nt] = __builtin_amdgcn_mfma_f32_16x16x32_bf16(a[1][kc].b, b.b, acc[1][nt], 0, 0, 0);
            }

#pragma unroll
        for (int g = 0; g < 2; ++g)
#pragma unroll
            for (int r = 0; r < 4; ++r) {
                int m = mbase + g * 16 + quad * 4 + r;  // C/D: col=lr, row=quad*4+r
                if (m < N) {
                    uint4 o;
                    o.x = pk_bf16(acc[g][0][r], acc[g][4][r]);
                    o.y = pk_bf16(acc[g][1][r], acc[g][5][r]);
                    o.z = pk_bf16(acc[g][2][r], acc[g][6][r]);
                    o.w = pk_bf16(acc[g][3][r], acc[g][7][r]);
                    *(uint4*)(yu + ((size_t)m * 7 + t) * 64 + lr * 4) = o;
                }
            }
    }
}

// ---- index width autodetect ----
__global__ void flag_k(const int* __restrict__ row, int* __restrict__ flag)
{
    if (threadIdx.x == 0 && blockIdx.x == 0) {
        int s = 0;
#pragma unroll
        for (int i = 1; i < 64; i += 2) s |= row[i];
        flag[0] = (s == 0) ? 1 : 0;
    }
}
__device__ inline int idx_at(const int* __restrict__ p, int e, int mode) {
    return p[mode ? (e << 1) : e];
}

// ---- count + bucket (t=6 dead: self slot overwritten) ----
__global__ void edge_k(const int* __restrict__ row, const int* __restrict__ col,
                       const int* __restrict__ et, const int* __restrict__ flag,
                       unsigned int* __restrict__ cnt, unsigned int* __restrict__ fill,
                       int* __restrict__ ebuf, int* __restrict__ ovf,
                       int* __restrict__ novf, int E, int N)
{
    int e = blockIdx.x * blockDim.x + threadIdx.x;
    if (e >= E) return;
    const int mode = flag[0];
    int r = idx_at(row, e, mode);
    int c = idx_at(col, e, mode);
    int t = idx_at(et,  e, mode);
    if ((unsigned)r >= (unsigned)N || (unsigned)c >= (unsigned)N || (unsigned)t >= 6u)
        return;
    atomicAdd(&cnt[r * 7 + t], 1u);
    unsigned pos = atomicAdd(&fill[r], 1u);
    if (pos < BUCKET_CAP) ebuf[(size_t)r * BUCKET_CAP + pos] = (c << 3) | t;
    else                  ovf[atomicAdd(novf, 1)] = e;
}

// ---- wave/node gather: batch-8 issue, pipelined metadata, fused BN stats ----
__global__ __launch_bounds__(256) void gather_k(
    const int* __restrict__ ebuf, const unsigned int* __restrict__ fill,
    const unsigned int* __restrict__ cnt, const unsigned int* __restrict__ yu,
    float* __restrict__ out, float* __restrict__ stats, int N, int nwaves)
{
    const int gw = (blockIdx.x * 256 + threadIdx.x) >> 6;
    const int l  = threadIdx.x & 63;
    const int clo = ((l & 3) << 4) + (l >> 2);     // channel of lo half; hi = clo+64
    float slo = 0.f, slo2 = 0.f, shi = 0.f, shi2 = 0.f;

    int r = gw;
    if (r < N) {
        // prologue: all metadata loads are independent -> one latency
        unsigned fl = fill[r];
        int      pf = ebuf[(size_t)r * BUCKET_CAP + l];   // lanes >= fill hold
        unsigned cw = (l < 7) ? cnt[r * 7 + l] : 1u;      // garbage, never shfl'd
        unsigned ps = yu[((size_t)r * 7 + 6) * 64 + l];   // self term, weight 1

        while (r < N) {
            const int rn  = r + nwaves;
            const int nE  = (int)min(fl, (unsigned)BUCKET_CAP);   // wave-uniform
            const float civ = 1.0f / (float)max(cw, 1u);          // recip once/node
            const int pay = pf;
            float a0 = bflo(ps), a1 = bfhi(ps);

            // ---- batch 0: up to 8 edge loads issued before any consume ----
            unsigned q[8]; float iv[8];
#pragma unroll
            for (int j = 0; j < 8; ++j)
                if (j < nE) {                         // uniform branch (scalar)
                    int pj = __shfl(pay, j);
                    q[j]  = yu[((size_t)(pj >> 3) * 7 + (pj & 7)) * 64 + l];
                    iv[j] = __shfl(civ, pj & 7);
                }

            // ---- prefetch next node metadata under the edge-load latency ----
            if (rn < N) {
                fl = fill[rn];
                pf = ebuf[(size_t)rn * BUCKET_CAP + l];
                cw = (l < 7) ? cnt[rn * 7 + l] : 1u;
                ps = yu[((size_t)rn * 7 + 6) * 64 + l];
            }

#pragma unroll
            for (int j = 0; j < 8; ++j)
                if (j < nE) { a0 += bflo(q[j]) * iv[j]; a1 += bfhi(q[j]) * iv[j]; }

            // ---- rare tail: degree > 8 (Poisson(7): ~27% of nodes take 1 extra
            //      batch, ~1% take 2) ----
            for (int k = 8; k < nE; k += 8) {
                const int rem = nE - k;               // wave-uniform
#pragma unroll
                for (int j = 0; j < 8; ++j)
                    if (j < rem) {
                        int pj = __shfl(pay, k + j);
                        q[j]  = yu[((size_t)(pj >> 3) * 7 + (pj & 7)) * 64 + l];
                        iv[j] = __shfl(civ, pj & 7);
                    }
#pragma unroll
                for (int j = 0; j < 8; ++j)
                    if (j < rem) { a0 += bflo(q[j]) * iv[j]; a1 += bfhi(q[j]) * iv[j]; }
            }

            out[(size_t)r * 128 + clo]      = a0;   // standard layout (permuted)
            out[(size_t)r * 128 + clo + 64] = a1;
            slo += a0; slo2 += a0 * a0; shi += a1; shi2 += a1 * a1;
            r = rn;
        }
    }

    __shared__ float rs[4][256];
    rs[0][threadIdx.x] = slo; rs[1][threadIdx.x] = slo2;
    rs[2][threadIdx.x] = shi; rs[3][threadIdx.x] = shi2;
    __syncthreads();
    if (threadIdx.x < 64) {
        float v0 = 0.f, v1 = 0.f, v2 = 0.f, v3 = 0.f;
#pragma unroll
        for (int w = 0; w < 4; ++w) {
            v0 += rs[0][w * 64 + threadIdx.x];
            v1 += rs[1][w * 64 + threadIdx.x];
            v2 += rs[2][w * 64 + threadIdx.x];
            v3 += rs[3][w * 64 + threadIdx.x];
        }
        atomicAdd(&stats[clo],           v0);
        atomicAdd(&stats[128 + clo],     v1);
        atomicAdd(&stats[clo + 64],      v2);
        atomicAdd(&stats[192 + clo],     v3);
    }
}

// ---- overflow repair: wave/edge; fixes out AND stats exactly via returned old ----
__global__ void ovf_k(const int* __restrict__ ovf, const int* __restrict__ novf,
                      const int* __restrict__ row, const int* __restrict__ col,
                      const int* __restrict__ et, const int* __restrict__ flag,
                      const unsigned int* __restrict__ yu,
                      const unsigned int* __restrict__ cnt,
                      float* __restrict__ out, float* __restrict__ stats, int nwaves)
{
    const int n = novf[0];
    if (n == 0) return;
    const int mode = flag[0];
    const int l = threadIdx.x & 63;
    const int clo = ((l & 3) << 4) + (l >> 2);
    for (int i = (blockIdx.x * 256 + threadIdx.x) >> 6; i < n; i += nwaves) {
        int e = ovf[i];
        int r = idx_at(row, e, mode);
        int c = idx_at(col, e, mode);
        int t = idx_at(et,  e, mode);
        float inv = 1.0f / (float)max(cnt[r * 7 + t], 1u);
        unsigned q = yu[((size_t)c * 7 + t) * 64 + l];
        float dlo = bflo(q) * inv, dhi = bfhi(q) * inv;
        float olo = atomicAdd(&out[(size_t)r * 128 + clo],      dlo);
        float ohi = atomicAdd(&out[(size_t)r * 128 + clo + 64], dhi);
        atomicAdd(&stats[clo],       dlo);
        atomicAdd(&stats[128 + clo], dlo * (2.f * olo + dlo));
        atomicAdd(&stats[clo + 64],  dhi);
        atomicAdd(&stats[192 + clo], dhi * (2.f * ohi + dhi));
    }
}

// ---- BN finalize: standard layout, coalesced vec4, no LDS ----
__global__ __launch_bounds__(256) void norm_k(
    float* __restrict__ out, const float* __restrict__ stats,
    const float* __restrict__ gamma, const float* __restrict__ beta, int N)
{
    const int c0 = (threadIdx.x * 4) & 127;     // grid stride is mult. of 128 elems
    const float invN = 1.0f / (float)N;
    f32x4 sc, bi;
#pragma unroll
    for (int j = 0; j < 4; ++j) {
        int c = c0 + j;
        float mean = stats[c] * invN;
        float var  = stats[128 + c] * invN - mean * mean;
        float s = gamma[c] * rsqrtf(var + 1e-5f);
        sc[j] = s; bi[j] = beta[c] - mean * s;
    }
    const size_t nv = (size_t)N * 32;           // vec4 count
    for (size_t v = (size_t)blockIdx.x * 256 + threadIdx.x; v < nv;
         v += (size_t)gridDim.x * 256) {
        f32x4 x = *(f32x4*)(out + v * 4);
#pragma unroll
        for (int j = 0; j < 4; ++j) x[j] = x[j] * sc[j] + bi[j];
        *(f32x4*)(out + v * 4) = x;
    }
}

extern "C" void kernel_launch(void* const* d_in, const int* in_sizes, int n_in,
                              void* d_out, int out_size, void* d_ws, size_t ws_size,
                              hipStream_t stream)
{
    const float* x     = (const float*)d_in[0];
    const int*   row   = (const int*)d_in[1];
    const int*   col   = (const int*)d_in[2];
    const int*   etype = (const int*)d_in[3];
    const float* w     = (const float*)d_in[4];
    const float* gamma = (const float*)d_in[5];
    const float* beta  = (const float*)d_in[6];
    float* out = (float*)d_out;

    const int N = in_sizes[0] / 128;   // 100000
    const int E = in_sizes[1];         // 700000

    char* ws = (char*)d_ws;
    unsigned int* yu   = (unsigned int*)ws;                            // N*7*64 u32
    short8*       wp   = (short8*)(ws + (size_t)N * 7 * 256);          // 229376 B
    unsigned int* cnt  = (unsigned int*)((char*)wp + 7 * 8 * 4 * 64 * 16); // 7N u32
    unsigned int* fill = (unsigned int*)((char*)cnt + (size_t)N * 7 * 4); // N u32
    int*          ebuf = (int*)((char*)fill + (size_t)N * 4);          // N*32 int
    int*          ovf  = (int*)((char*)ebuf + (size_t)N * BUCKET_CAP * 4); // E int
    float*        stats= (float*)((char*)ovf + (size_t)E * 4);         // 256 f32
    int*          flag = (int*)((char*)stats + 256 * 4);               // 1 int
    int*          novf = flag + 1;                                     // 1 int

    hipMemsetAsync(cnt,  0, (size_t)N * 7 * 4, stream);
    hipMemsetAsync(fill, 0, (size_t)N * 4,     stream);
    hipMemsetAsync(stats, 0, 256 * 4 + 8,      stream);

    flag_k<<<1, 64, 0, stream>>>(row, flag);
    pack_w<<<(7 * 8 * 4 * 64 + 255) / 256, 256, 0, stream>>>(w, wp);
    edge_k<<<(E + 255) / 256, 256, 0, stream>>>(row, col, etype, flag,
                                                cnt, fill, ebuf, ovf, novf, E, N);
    gemm_xw<<<(N + 127) / 128, 256, 0, stream>>>(x, (const uint4*)wp, yu, N);
    gather_k<<<2048, 256, 0, stream>>>(ebuf, fill, cnt, yu, out, stats, N, 8192);
    ovf_k<<<64, 256, 0, stream>>>(ovf, novf, row, col, etype, flag,
                                  yu, cnt, out, stats, 256);
    norm_k<<<2048, 256, 0, stream>>>(out, stats, gamma, beta, N);
}